// Round 1
// baseline (183.976 us; speedup 1.0000x reference)
//
#include <hip/hip_runtime.h>
#include <hip/hip_bf16.h>

// CorrelationNetwork fused kernels for MI355X (gfx950) — round 5.
// R4 post-mortem: top-5 dispatches are all 42us harness fills => both kernels
// are < 42us. corr's remaining cost is structural: 3 barriers/tile and an
// At LDS round-trip (build h1 -> LDS -> re-read) + W2s LDS re-reads
// (128 KB/tile) + Aj L2 re-fetch per tile. MFMA floor is only 8.3us.
// R5: h1 fragments are built directly in the consuming wave's registers
// (never stored); W2 half lives in 64 VGPRs per wave (zero LDS reads);
// Aj/Ai staged once per block into pad-132 LDS rows (b128 conflict floor,
// immediate-offset ds_reads); part[] double-buffered -> ONE barrier/tile.

typedef __bf16 bf16x8 __attribute__((ext_vector_type(8)));
typedef float f32x4 __attribute__((ext_vector_type(4)));

#define B_SZ 128
#define N_SZ 64
#define H_SZ 128

// ---- setup: blocks 0..2047 prepass (4 bn-rows each), 2048..2111 W2->W2T bf16,
//      block 2112 softmax(mixing_weights)   (unchanged from R4 — proven)
__global__ __launch_bounds__(256) void setup_kernel(
    const float* __restrict__ af, const float* __restrict__ W1,
    const float* __restrict__ b1, const float* __restrict__ W2,
    const float* __restrict__ mw, float* __restrict__ AiP,
    float* __restrict__ Aj, unsigned short* __restrict__ W2T,
    float* __restrict__ outw)
{
  const int blk = blockIdx.x;
  const int tid = threadIdx.x;

  if (blk < 2048) {
    // prepass: AiP[bn,h] = sum_f f[bn,f]*W1[f,h] + b1[h]; Aj via W1[64+f]
    __shared__ float fl[4 * 64];
    const int bn0 = blk << 2;
    fl[tid] = af[((bn0 + (tid >> 6)) << 7) + (tid & 63)];
    __syncthreads();
    const int h    = tid & 127;
    const int half = tid >> 7;                 // 0 -> Ai, 1 -> Aj
    const float* Wp = W1 + ((half << 6) << 7) + h;
    float acc0 = 0.f, acc1 = 0.f, acc2 = 0.f, acc3 = 0.f;
#pragma unroll
    for (int fq = 0; fq < 16; ++fq) {
      const float w0 = Wp[(fq * 4 + 0) << 7];
      const float w1v = Wp[(fq * 4 + 1) << 7];
      const float w2v = Wp[(fq * 4 + 2) << 7];
      const float w3v = Wp[(fq * 4 + 3) << 7];
      const float4 f0 = *(const float4*)&fl[0 * 64 + (fq << 2)];
      const float4 f1 = *(const float4*)&fl[1 * 64 + (fq << 2)];
      const float4 f2 = *(const float4*)&fl[2 * 64 + (fq << 2)];
      const float4 f3 = *(const float4*)&fl[3 * 64 + (fq << 2)];
      acc0 = fmaf(f0.x, w0, fmaf(f0.y, w1v, fmaf(f0.z, w2v, fmaf(f0.w, w3v, acc0))));
      acc1 = fmaf(f1.x, w0, fmaf(f1.y, w1v, fmaf(f1.z, w2v, fmaf(f1.w, w3v, acc1))));
      acc2 = fmaf(f2.x, w0, fmaf(f2.y, w1v, fmaf(f2.z, w2v, fmaf(f2.w, w3v, acc2))));
      acc3 = fmaf(f3.x, w0, fmaf(f3.y, w1v, fmaf(f3.z, w2v, fmaf(f3.w, w3v, acc3))));
    }
    if (half == 0) {
      const float bb = b1[h];
      AiP[((bn0 + 0) << 7) + h] = acc0 + bb;
      AiP[((bn0 + 1) << 7) + h] = acc1 + bb;
      AiP[((bn0 + 2) << 7) + h] = acc2 + bb;
      AiP[((bn0 + 3) << 7) + h] = acc3 + bb;
    } else {
      Aj[((bn0 + 0) << 7) + h] = acc0;
      Aj[((bn0 + 1) << 7) + h] = acc1;
      Aj[((bn0 + 2) << 7) + h] = acc2;
      Aj[((bn0 + 3) << 7) + h] = acc3;
    }
  } else if (blk < 2112) {
    // W2 (128x128, k-major) -> W2T (n-major) bf16
    int idx = ((blk - 2048) << 8) + tid;       // 0..16383
    int k = idx >> 7, n = idx & 127;
    unsigned u = __float_as_uint(W2[idx]);
    u += 0x7fffu + ((u >> 16) & 1u);
    W2T[(n << 7) + k] = (unsigned short)(u >> 16);
  } else {
    // softmax over 64 mixing weights
    if (tid < 64) {
      float v = mw[tid];
      float m = v;
      for (int off = 32; off > 0; off >>= 1) m = fmaxf(m, __shfl_xor(m, off));
      float e = expf(v - m);
      float s = e;
      for (int off = 32; off > 0; off >>= 1) s += __shfl_xor(s, off);
      outw[tid] = e / s;
    }
  }
}

// ---- main kernel: 512 blocks x 512 thr (2/CU), block = (b, 8 i-pairs).
// Wave (wm = wave&1 -> 64 w2cols in regs, wn = wave>>1 -> 32 rows).
// Per K-step: build hv fragment in registers from LDS Aj/Ai (f32, pad-132
// rows, immediate-offset b128 reads) -> relu -> RNE bf16 -> 4 MFMAs with
// register-resident W2 frags. One __syncthreads per tile (part db).
__global__ __launch_bounds__(512, 4) void corr_kernel(
    const float* __restrict__ AiP, const float* __restrict__ Aj,
    const unsigned short* __restrict__ W2T,
    const float* __restrict__ b2, const float* __restrict__ w3,
    const float* __restrict__ b3, float* __restrict__ out)
{
  // pad rows to 132 floats (528 B): bank-group = (j + 2g + h) mod 8 ->
  // uniform 8 lanes/group = b128 floor; kt offset is a uniform immediate.
  __shared__ __align__(16) float AjF[64 * 132];   // 33 KB
  __shared__ __align__(16) float AiF[16 * 132];   // 8.25 KB
  __shared__ float b2s[128], w3s[128];
  __shared__ float part[2][2][128];               // [tile&1][wm][row]

  const int tid  = threadIdx.x;
  const int lane = tid & 63;
  const int wave = tid >> 6;            // 0..7
  const int c = lane & 15, g = lane >> 4;
  const int wm = wave & 1;              // w2col half (64 cols)
  const int wn = wave >> 1;             // row quarter (32 rows)

  const int blk = blockIdx.x;
  const int b   = blk >> 2;             // 0..127
  const int ip0 = (blk & 3) << 3;       // this block's 8 i-pairs

  // ---- stage Aj (64 rows), Ai (16 rows), b2/w3 — once per block, coalesced
  {
    const float4* src = (const float4*)(Aj + (b << 13));
#pragma unroll
    for (int p = 0; p < 4; ++p) {
      const int idx = (p << 9) + tid;           // 0..2047 float4s
      const int r = idx >> 5, u = idx & 31;
      *(float4*)&AjF[r * 132 + (u << 2)] = src[idx];
    }
    const float4* srcA = (const float4*)(AiP + (((b << 6) + (ip0 << 1)) << 7));
    {
      const int r = tid >> 5, u = tid & 31;
      *(float4*)&AiF[r * 132 + (u << 2)] = srcA[tid];
    }
    if (tid < 128) b2s[tid] = b2[tid];
    else if (tid < 256) w3s[tid - 128] = w3[tid - 128];
  }

  // ---- W2 fragments -> registers (64 VGPR), once per block.
  // A-frag lane(c,g): m = wm*64 + mt*16 + c, k = kt*32 + g*8 + e.
  bf16x8 w2r[4][4];
#pragma unroll
  for (int mt = 0; mt < 4; ++mt)
#pragma unroll
    for (int kt = 0; kt < 4; ++kt)
      w2r[mt][kt] = *(const bf16x8*)&W2T[(((wm << 6) + (mt << 4) + c) << 7) +
                                         (kt << 5) + (g << 3)];
  const float bias3 = b3[0];

  // per-lane LDS fragment bases (fixed for whole kernel)
  const int j0 = ((wn << 5) + c) & 63;          // tn = 0 rows
  const int j1 = ((wn << 5) + 16 + c) & 63;     // tn = 1 rows
  const float* ajb0 = &AjF[j0 * 132 + (g << 3)];
  const float* ajb1 = &AjF[j1 * 132 + (g << 3)];
  const int i_sel = wn >> 1;                    // row>=64 -> second i

  __syncthreads();

  for (int t = 0; t < 8; ++t) {
    const float* aib = &AiF[((t << 1) + i_sel) * 132 + (g << 3)];
    float s[2];

#pragma unroll
    for (int tn = 0; tn < 2; ++tn) {
      const float* ajb = tn ? ajb1 : ajb0;

      f32x4 acc[4];
#pragma unroll
      for (int mt = 0; mt < 4; ++mt)
        acc[mt] = *(const f32x4*)&b2s[(wm << 6) + (mt << 4) + (g << 2)];

#pragma unroll
      for (int kt = 0; kt < 4; ++kt) {
        // h1[row][kt*32 + g*8 + 0..7] = relu(Ai + Aj), built in-register
        const f32x4 a0 = *(const f32x4*)(aib + (kt << 5));
        const f32x4 a1 = *(const f32x4*)(aib + (kt << 5) + 4);
        const f32x4 c0 = *(const f32x4*)(ajb + (kt << 5));
        const f32x4 c1 = *(const f32x4*)(ajb + (kt << 5) + 4);
        f32x4 h0 = a0 + c0;
        f32x4 h1v = a1 + c1;
        bf16x8 hv;
#pragma unroll
        for (int e = 0; e < 4; ++e) {
          hv[e]     = (__bf16)fmaxf(h0[e], 0.f);
          hv[e + 4] = (__bf16)fmaxf(h1v[e], 0.f);
        }
#pragma unroll
        for (int mt = 0; mt < 4; ++mt)
          acc[mt] = __builtin_amdgcn_mfma_f32_16x16x32_bf16(
              w2r[mt][kt], hv, acc[mt], 0, 0, 0);
      }

      // epilogue reduce: relu(h2) . w3 (in-lane over mt,p; shfl over g)
      float sv = 0.f;
#pragma unroll
      for (int mt = 0; mt < 4; ++mt) {
        const f32x4 wv3 = *(const f32x4*)&w3s[(wm << 6) + (mt << 4) + (g << 2)];
#pragma unroll
        for (int p = 0; p < 4; ++p)
          sv = fmaf(fmaxf(acc[mt][p], 0.f), wv3[p], sv);
      }
      sv += __shfl_xor(sv, 16);
      sv += __shfl_xor(sv, 32);
      s[tn] = sv;
    }

    const int pb = t & 1;
    if (g == 0) {                              // 16 lanes, conflict-free
      part[pb][wm][(wn << 5) + c]      = s[0];
      part[pb][wm][(wn << 5) + 16 + c] = s[1];
    }

    __syncthreads();                           // ONE barrier per tile

    if (tid < 128) {
      const float v = part[pb][0][tid] + part[pb][1][tid] + bias3;
      out[(b << 12) + ((ip0 + t) << 7) + tid] = 1.f / (1.f + __expf(-v));
    }
  }
}

extern "C" void kernel_launch(void* const* d_in, const int* in_sizes, int n_in,
                              void* d_out, int out_size, void* d_ws,
                              size_t ws_size, hipStream_t stream)
{
  const float* af = (const float*)d_in[0];   // (128,64,128)
  const float* W1 = (const float*)d_in[1];   // (128,128)
  const float* b1 = (const float*)d_in[2];   // (128,)
  const float* W2 = (const float*)d_in[3];   // (128,128)
  const float* b2 = (const float*)d_in[4];   // (128,)
  const float* w3 = (const float*)d_in[5];   // (128,)
  const float* b3 = (const float*)d_in[6];   // (1,)
  const float* mw = (const float*)d_in[7];   // (64,)
  float* out = (float*)d_out;                // 524288 corr + 64 weights

  float* AiP = (float*)d_ws;                           // 4 MB
  float* Aj  = AiP + B_SZ * N_SZ * H_SZ;               // 4 MB
  unsigned short* W2T = (unsigned short*)(Aj + B_SZ * N_SZ * H_SZ);  // 32 KB

  setup_kernel<<<2113, 256, 0, stream>>>(af, W1, b1, W2, mw, AiP, Aj, W2T,
                                         out + B_SZ * N_SZ * N_SZ);
  corr_kernel<<<512, 512, 0, stream>>>(AiP, Aj, W2T, b2, w3, b3, out);
}

// Round 2
// 102.101 us; speedup vs baseline: 1.8019x; 1.8019x over previous
//
#include <hip/hip_runtime.h>
#include <hip/hip_bf16.h>

// CorrelationNetwork fused kernels for MI355X (gfx950) — round 6.
// R5 post-mortem: w2r[4][4] (64 VGPR) + acc overflowed the 128-reg cap from
// __launch_bounds__(512,4) -> compiler spilled W2 frags to scratch.
// Evidence: VGPR_Count=64, WRITE_SIZE 68MB (= 64 regs x 4B x 512thr x 512blk
// spill-store), FETCH_SIZE 287MB (= 16 reloads of 64MB/4), corr 111us.
// R6: W2 back to LDS (R4's proven swizzled W2s, staged once/block); keep
// R5's wins: in-register h1 build (no At round-trip), Aj/Ai staged once in
// pad-132 f32 LDS, ONE barrier/tile (part double-buffered). kt-loop hoisted
// outside tn so W2 frags are read once per kt (acc[4][2], ~95 VGPR, no spill).

typedef __bf16 bf16x8 __attribute__((ext_vector_type(8)));
typedef float f32x4 __attribute__((ext_vector_type(4)));

#define B_SZ 128
#define N_SZ 64
#define H_SZ 128

// ---- setup: blocks 0..2047 prepass (4 bn-rows each), 2048..2111 W2->W2T bf16,
//      block 2112 softmax(mixing_weights)   (unchanged — proven)
__global__ __launch_bounds__(256) void setup_kernel(
    const float* __restrict__ af, const float* __restrict__ W1,
    const float* __restrict__ b1, const float* __restrict__ W2,
    const float* __restrict__ mw, float* __restrict__ AiP,
    float* __restrict__ Aj, unsigned short* __restrict__ W2T,
    float* __restrict__ outw)
{
  const int blk = blockIdx.x;
  const int tid = threadIdx.x;

  if (blk < 2048) {
    // prepass: AiP[bn,h] = sum_f f[bn,f]*W1[f,h] + b1[h]; Aj via W1[64+f]
    __shared__ float fl[4 * 64];
    const int bn0 = blk << 2;
    fl[tid] = af[((bn0 + (tid >> 6)) << 7) + (tid & 63)];
    __syncthreads();
    const int h    = tid & 127;
    const int half = tid >> 7;                 // 0 -> Ai, 1 -> Aj
    const float* Wp = W1 + ((half << 6) << 7) + h;
    float acc0 = 0.f, acc1 = 0.f, acc2 = 0.f, acc3 = 0.f;
#pragma unroll
    for (int fq = 0; fq < 16; ++fq) {
      const float w0 = Wp[(fq * 4 + 0) << 7];
      const float w1v = Wp[(fq * 4 + 1) << 7];
      const float w2v = Wp[(fq * 4 + 2) << 7];
      const float w3v = Wp[(fq * 4 + 3) << 7];
      const float4 f0 = *(const float4*)&fl[0 * 64 + (fq << 2)];
      const float4 f1 = *(const float4*)&fl[1 * 64 + (fq << 2)];
      const float4 f2 = *(const float4*)&fl[2 * 64 + (fq << 2)];
      const float4 f3 = *(const float4*)&fl[3 * 64 + (fq << 2)];
      acc0 = fmaf(f0.x, w0, fmaf(f0.y, w1v, fmaf(f0.z, w2v, fmaf(f0.w, w3v, acc0))));
      acc1 = fmaf(f1.x, w0, fmaf(f1.y, w1v, fmaf(f1.z, w2v, fmaf(f1.w, w3v, acc1))));
      acc2 = fmaf(f2.x, w0, fmaf(f2.y, w1v, fmaf(f2.z, w2v, fmaf(f2.w, w3v, acc2))));
      acc3 = fmaf(f3.x, w0, fmaf(f3.y, w1v, fmaf(f3.z, w2v, fmaf(f3.w, w3v, acc3))));
    }
    if (half == 0) {
      const float bb = b1[h];
      AiP[((bn0 + 0) << 7) + h] = acc0 + bb;
      AiP[((bn0 + 1) << 7) + h] = acc1 + bb;
      AiP[((bn0 + 2) << 7) + h] = acc2 + bb;
      AiP[((bn0 + 3) << 7) + h] = acc3 + bb;
    } else {
      Aj[((bn0 + 0) << 7) + h] = acc0;
      Aj[((bn0 + 1) << 7) + h] = acc1;
      Aj[((bn0 + 2) << 7) + h] = acc2;
      Aj[((bn0 + 3) << 7) + h] = acc3;
    }
  } else if (blk < 2112) {
    // W2 (128x128, k-major) -> W2T (n-major) bf16
    int idx = ((blk - 2048) << 8) + tid;       // 0..16383
    int k = idx >> 7, n = idx & 127;
    unsigned u = __float_as_uint(W2[idx]);
    u += 0x7fffu + ((u >> 16) & 1u);
    W2T[(n << 7) + k] = (unsigned short)(u >> 16);
  } else {
    // softmax over 64 mixing weights
    if (tid < 64) {
      float v = mw[tid];
      float m = v;
      for (int off = 32; off > 0; off >>= 1) m = fmaxf(m, __shfl_xor(m, off));
      float e = expf(v - m);
      float s = e;
      for (int off = 32; off > 0; off >>= 1) s += __shfl_xor(s, off);
      outw[tid] = e / s;
    }
  }
}

// ---- main kernel: 512 blocks x 512 thr (2/CU), block = (b, 8 i-pairs).
// Wave: wm = wave&1 (w2col half), wn = wave>>1 (row quarter, 32 rows).
// Per kt: 4 b128 W2 frags from swizzled LDS + h1 frags built in registers
// from LDS Aj/Ai (f32, pad-132 rows) -> relu -> RNE bf16 -> 8 MFMAs.
// One __syncthreads per tile (part double-buffered).
__global__ __launch_bounds__(512, 4) void corr_kernel(
    const float* __restrict__ AiP, const float* __restrict__ Aj,
    const unsigned short* __restrict__ W2T,
    const float* __restrict__ b2, const float* __restrict__ w3,
    const float* __restrict__ b3, float* __restrict__ out)
{
  __shared__ __align__(16) unsigned short W2s[128 * 128];  // 32 KB, swizzled
  __shared__ __align__(16) float AjF[64 * 132];            // 33 KB, pad-132
  __shared__ __align__(16) float AiF[16 * 132];            // 8.25 KB
  __shared__ float b2s[128], w3s[128];
  __shared__ float part[2][2][128];                        // [tile&1][wm][row]

  const int tid  = threadIdx.x;
  const int lane = tid & 63;
  const int wave = tid >> 6;            // 0..7
  const int c = lane & 15, g = lane >> 4;
  const int wm = wave & 1;              // w2col half (64 cols)
  const int wn = wave >> 1;             // row quarter (32 rows)

  const int blk = blockIdx.x;
  const int b   = blk >> 2;             // 0..127
  const int ip0 = (blk & 3) << 3;       // this block's 8 i-pairs

  // ---- stage W2T -> W2s swizzled (R4-proven), once per block
  {
    const uint4* src = (const uint4*)W2T;     // 2048 x 16B chunks
#pragma unroll
    for (int it = 0; it < 4; ++it) {
      const int idx = (it << 9) + tid;        // 0..2047
      const int n = idx >> 4, e = idx & 15;
      const uint4 v = src[idx];
      *(uint4*)&W2s[(n << 7) + ((e ^ (n & 15)) << 3)] = v;
    }
  }
  // ---- stage Aj (64 rows), Ai (16 rows), b2/w3 — once per block, coalesced
  {
    const float4* src = (const float4*)(Aj + (b << 13));
#pragma unroll
    for (int p = 0; p < 4; ++p) {
      const int idx = (p << 9) + tid;         // 0..2047 float4s
      const int r = idx >> 5, u = idx & 31;
      *(float4*)&AjF[r * 132 + (u << 2)] = src[idx];
    }
    const float4* srcA = (const float4*)(AiP + (((b << 6) + (ip0 << 1)) << 7));
    {
      const int r = tid >> 5, u = tid & 31;
      *(float4*)&AiF[r * 132 + (u << 2)] = srcA[tid];
    }
    if (tid < 128) b2s[tid] = b2[tid];
    else if (tid < 256) w3s[tid - 128] = w3[tid - 128];
  }

  const float bias3 = b3[0];

  // per-lane LDS fragment bases (fixed for whole kernel)
  const int j0 = ((wn << 5) + c) & 63;          // tn = 0 rows
  const int j1 = ((wn << 5) + 16 + c) & 63;     // tn = 1 rows
  const float* ajb0 = &AjF[j0 * 132 + (g << 3)];
  const float* ajb1 = &AjF[j1 * 132 + (g << 3)];
  const int i_sel = wn >> 1;                    // row>=64 -> second i

  __syncthreads();

  for (int t = 0; t < 8; ++t) {
    const float* aib = &AiF[((t << 1) + i_sel) * 132 + (g << 3)];

    // ---- MFMA: acc init = b2 (D = A*B + C)
    f32x4 acc[4][2];
#pragma unroll
    for (int mt = 0; mt < 4; ++mt) {
      const f32x4 bv = *(const f32x4*)&b2s[(wm << 6) + (mt << 4) + (g << 2)];
      acc[mt][0] = bv;
      acc[mt][1] = bv;
    }

#pragma unroll
    for (int kt = 0; kt < 4; ++kt) {
      // W2 frags from swizzled LDS (row low4 == c)
      const int es = ((kt << 2) + g) ^ c;
      bf16x8 wv[4];
#pragma unroll
      for (int mt = 0; mt < 4; ++mt)
        wv[mt] = *(const bf16x8*)&W2s[(((wm << 6) + (mt << 4) + c) << 7) + (es << 3)];

      // h1 fragments built in registers: h1[row][kt*32 + g*8 + e]
      const f32x4 a0 = *(const f32x4*)(aib + (kt << 5));
      const f32x4 a1 = *(const f32x4*)(aib + (kt << 5) + 4);
      bf16x8 hv[2];
#pragma unroll
      for (int tn = 0; tn < 2; ++tn) {
        const float* ajb = tn ? ajb1 : ajb0;
        const f32x4 c0 = *(const f32x4*)(ajb + (kt << 5));
        const f32x4 c1 = *(const f32x4*)(ajb + (kt << 5) + 4);
        const f32x4 h0 = a0 + c0;
        const f32x4 h1v = a1 + c1;
#pragma unroll
        for (int e = 0; e < 4; ++e) {
          hv[tn][e]     = (__bf16)fmaxf(h0[e], 0.f);
          hv[tn][e + 4] = (__bf16)fmaxf(h1v[e], 0.f);
        }
      }

#pragma unroll
      for (int mt = 0; mt < 4; ++mt)
#pragma unroll
        for (int tn = 0; tn < 2; ++tn)
          acc[mt][tn] = __builtin_amdgcn_mfma_f32_16x16x32_bf16(
              wv[mt], hv[tn], acc[mt][tn], 0, 0, 0);
    }

    // ---- epilogue: relu(h2).w3 in-lane over (mt,p), shfl over g, LDS over wm
    float s0 = 0.f, s1 = 0.f;
#pragma unroll
    for (int mt = 0; mt < 4; ++mt) {
      const f32x4 wv3 = *(const f32x4*)&w3s[(wm << 6) + (mt << 4) + (g << 2)];
#pragma unroll
      for (int p = 0; p < 4; ++p) {
        s0 = fmaf(fmaxf(acc[mt][0][p], 0.f), wv3[p], s0);
        s1 = fmaf(fmaxf(acc[mt][1][p], 0.f), wv3[p], s1);
      }
    }
    s0 += __shfl_xor(s0, 16);
    s0 += __shfl_xor(s0, 32);
    s1 += __shfl_xor(s1, 16);
    s1 += __shfl_xor(s1, 32);

    const int pb = t & 1;
    if (g == 0) {                              // 16 lanes, conflict-free
      part[pb][wm][(wn << 5) + c]      = s0;
      part[pb][wm][(wn << 5) + 16 + c] = s1;
    }

    __syncthreads();                           // ONE barrier per tile

    if (tid < 128) {
      const float v = part[pb][0][tid] + part[pb][1][tid] + bias3;
      out[(b << 12) + ((ip0 + t) << 7) + tid] = 1.f / (1.f + __expf(-v));
    }
  }
}

extern "C" void kernel_launch(void* const* d_in, const int* in_sizes, int n_in,
                              void* d_out, int out_size, void* d_ws,
                              size_t ws_size, hipStream_t stream)
{
  const float* af = (const float*)d_in[0];   // (128,64,128)
  const float* W1 = (const float*)d_in[1];   // (128,128)
  const float* b1 = (const float*)d_in[2];   // (128,)
  const float* W2 = (const float*)d_in[3];   // (128,128)
  const float* b2 = (const float*)d_in[4];   // (128,)
  const float* w3 = (const float*)d_in[5];   // (128,)
  const float* b3 = (const float*)d_in[6];   // (1,)
  const float* mw = (const float*)d_in[7];   // (64,)
  float* out = (float*)d_out;                // 524288 corr + 64 weights

  float* AiP = (float*)d_ws;                           // 4 MB
  float* Aj  = AiP + B_SZ * N_SZ * H_SZ;               // 4 MB
  unsigned short* W2T = (unsigned short*)(Aj + B_SZ * N_SZ * H_SZ);  // 32 KB

  setup_kernel<<<2113, 256, 0, stream>>>(af, W1, b1, W2, mw, AiP, Aj, W2T,
                                         out + B_SZ * N_SZ * N_SZ);
  corr_kernel<<<512, 512, 0, stream>>>(AiP, Aj, W2T, b2, w3, b3, out);
}